// Round 5
// baseline (523.376 us; speedup 1.0000x reference)
//
#include <hip/hip_runtime.h>

// perm_inv_n: x[256,512,64] fp32 ->
//   per z (flat): cs[64] | gram[64x64] | ss[64] | cs^2[64] | (gram x cs)[64^3]
// MEASUREMENT ROUND: kernels identical to round 4, but bodies repeated
// idempotently (k_stats x8, k_h5 store loop x4) so their dispatch durations
// exceed the 173us harness fill and appear in rocprof top-5 WITH counters.
// asm memory clobbers per rep prevent CSE/DSE from collapsing repeats.
// Attribution: round4 total = F + S + H; this total = F + 8S + 4H.
#define Z_DIM 256
#define A_DIM 512
#define B_DIM 64
#define PER_Z 266432
#define GRAM_OFF 64
#define H3_OFF 4160
#define H4_OFF 4224
#define H5_OFF 4288
#define RS 8
#define RH 4

typedef float f4v __attribute__((ext_vector_type(4)));

__device__ __forceinline__ void wave_store_tile(float* area, const float acc[8][8],
                                                int R, int C) {
#pragma unroll
    for (int i = 0; i < 8; i++) {
        *(float4*)&area[(R + i) * B_DIM + C] =
            make_float4(acc[i][0], acc[i][1], acc[i][2], acc[i][3]);
        *(float4*)&area[(R + i) * B_DIM + C + 4] =
            make_float4(acc[i][4], acc[i][5], acc[i][6], acc[i][7]);
    }
}

__device__ __forceinline__ void wave_add_tile(const float* area, float acc[8][8],
                                              int R, int C) {
#pragma unroll
    for (int i = 0; i < 8; i++) {
        float4 p0 = *(const float4*)&area[(R + i) * B_DIM + C];
        float4 p1 = *(const float4*)&area[(R + i) * B_DIM + C + 4];
        acc[i][0] += p0.x; acc[i][1] += p0.y; acc[i][2] += p0.z; acc[i][3] += p0.w;
        acc[i][4] += p1.x; acc[i][5] += p1.y; acc[i][6] += p1.z; acc[i][7] += p1.w;
    }
}

__global__ __launch_bounds__(512) void k_stats(const float* __restrict__ x,
                                               float* __restrict__ out) {
    __shared__ float sx[2][B_DIM * B_DIM];  // 32 KB: dbuf staging, then 2 reduce areas
    __shared__ float csred[8][B_DIM];       // 2 KB cs partials

    const int z = blockIdx.x;
    const int t = threadIdx.x;
    const int w = t >> 6;       // wave 0..7
    const int l = t & 63;
    const int R = (l >> 3) * 8; // gram row-tile base
    const int C = (l & 7) * 8;  // gram col-tile base

    const float* xz = x + (size_t)z * (A_DIM * B_DIM);
    float* oz = out + (size_t)z * PER_Z;

#pragma unroll 1
    for (int rep = 0; rep < RS; ++rep) {
        asm volatile("" ::: "memory");  // block CSE/DSE across reps

        float acc[8][8];
#pragma unroll
        for (int i = 0; i < 8; i++)
#pragma unroll
            for (int j = 0; j < 8; j++) acc[i][j] = 0.f;
        float csa[8];
#pragma unroll
        for (int j = 0; j < 8; j++) csa[j] = 0.f;

        // prologue: stage chunk 0 (64 rows = 16 KB = 1024 float4, 2 per thread)
        {
            const float4* src = (const float4*)xz;
            float4 r0 = src[t], r1 = src[t + 512];
            ((float4*)sx[0])[t] = r0;
            ((float4*)sx[0])[t + 512] = r1;
        }
        __syncthreads();

        for (int c = 0; c < 8; ++c) {
            const float* buf = sx[c & 1];
            float4 n0, n1;
            if (c < 7) {  // issue next chunk's loads BEFORE compute
                const float4* src = (const float4*)(xz + (size_t)(c + 1) * 64 * B_DIM);
                n0 = src[t];
                n1 = src[t + 512];
            }
            const float* rbase = buf + (w * 8) * B_DIM;
#pragma unroll
            for (int k = 0; k < 8; ++k) {
                const float* row = rbase + k * B_DIM;
                float4 b0 = *(const float4*)(row + R);
                float4 b1 = *(const float4*)(row + R + 4);
                float4 c0 = *(const float4*)(row + C);
                float4 c1 = *(const float4*)(row + C + 4);
                float xb[8] = {b0.x, b0.y, b0.z, b0.w, b1.x, b1.y, b1.z, b1.w};
                float xc[8] = {c0.x, c0.y, c0.z, c0.w, c1.x, c1.y, c1.z, c1.w};
#pragma unroll
                for (int i = 0; i < 8; i++)
#pragma unroll
                    for (int j = 0; j < 8; j++)
                        acc[i][j] = fmaf(xb[i], xc[j], acc[i][j]);
                if (l < 8) {
#pragma unroll
                    for (int j = 0; j < 8; j++) csa[j] += xc[j];
                }
            }
            if (c < 7) {
                float* nb = sx[(c + 1) & 1];
                ((float4*)nb)[t] = n0;
                ((float4*)nb)[t + 512] = n1;
            }
            __syncthreads();
        }

        if (l < 8) {
#pragma unroll
            for (int j = 0; j < 8; j++) csred[w][l * 8 + j] = csa[j];
        }

        // tree-reduce 8 wave partials using sx[0]/sx[1] as two 16 KB areas
        float* area0 = sx[0];
        float* area1 = sx[1];
        if (w == 4) wave_store_tile(area0, acc, R, C);
        if (w == 5) wave_store_tile(area1, acc, R, C);
        __syncthreads();
        if (w == 0) wave_add_tile(area0, acc, R, C);
        if (w == 1) wave_add_tile(area1, acc, R, C);
        __syncthreads();
        if (w == 6) wave_store_tile(area0, acc, R, C);
        if (w == 7) wave_store_tile(area1, acc, R, C);
        __syncthreads();
        if (w == 2) wave_add_tile(area0, acc, R, C);
        if (w == 3) wave_add_tile(area1, acc, R, C);
        __syncthreads();
        if (w == 2) wave_store_tile(area0, acc, R, C);
        if (w == 3) wave_store_tile(area1, acc, R, C);
        __syncthreads();
        if (w == 0) wave_add_tile(area0, acc, R, C);
        if (w == 1) wave_add_tile(area1, acc, R, C);
        __syncthreads();
        if (w == 1) wave_store_tile(area0, acc, R, C);
        __syncthreads();

        if (w == 0) {
            wave_add_tile(area0, acc, R, C);
#pragma unroll
            for (int i = 0; i < 8; i++) {
                *(float4*)&oz[GRAM_OFF + (size_t)(R + i) * B_DIM + C] =
                    make_float4(acc[i][0], acc[i][1], acc[i][2], acc[i][3]);
                *(float4*)&oz[GRAM_OFF + (size_t)(R + i) * B_DIM + C + 4] =
                    make_float4(acc[i][4], acc[i][5], acc[i][6], acc[i][7]);
            }
            if ((l >> 3) == (l & 7)) {
#pragma unroll
                for (int i = 0; i < 8; i++) oz[H3_OFF + R + i] = acc[i][i];
            }
            float cs = 0.f;
#pragma unroll
            for (int ww = 0; ww < 8; ww++) cs += csred[ww][l];
            oz[l] = cs;
            oz[H4_OFF + l] = cs * cs;
        }
        __syncthreads();  // protect sx/csred from next rep's staging (wave 0 still reading)
    }
}

// h5[b][c][d] = gram[b*64+c] * cs[d].  grid = 256 z * 16 slabs, 256 threads.
// Slab s covers bc in [s*256, s*256+256): 64 KB contiguous stores per block.
// Store loop repeated RH times (idempotent) for measurement.
__global__ __launch_bounds__(256) void k_h5(const float* __restrict__ outc,
                                            float* __restrict__ out) {
    __shared__ __align__(16) float sgr[256];
    __shared__ __align__(16) float scs[B_DIM];

    const int z = blockIdx.x >> 4;
    const int s = blockIdx.x & 15;
    const int t = threadIdx.x;

    const float* oz = outc + (size_t)z * PER_Z;
    sgr[t] = oz[GRAM_OFF + s * 256 + t];   // one coalesced 1 KB load
    if (t < B_DIM) scs[t] = oz[t];
    __syncthreads();

    const int dg = t & 15;   // d-group: d = dg*4 .. dg*4+3
    const int bq = t >> 4;   // 0..15
    const f4v c4 = *(const f4v*)&scs[dg * 4];

    f4v* o5 = (f4v*)(out + (size_t)z * PER_Z + H5_OFF);
    const size_t base = (size_t)s * 4096 + bq * 16 + dg;
#pragma unroll 1
    for (int rep = 0; rep < RH; ++rep) {
        asm volatile("" ::: "memory");  // block DSE across reps
#pragma unroll
        for (int i = 0; i < 16; i++) {
            const float g = sgr[bq + i * 16];   // LDS broadcast, ~free
            f4v v = {g * c4.x, g * c4.y, g * c4.z, g * c4.w};
            o5[base + (size_t)i * 256] = v;     // per wave: 1 KB contiguous segment
        }
    }
}

extern "C" void kernel_launch(void* const* d_in, const int* in_sizes, int n_in,
                              void* d_out, int out_size, void* d_ws, size_t ws_size,
                              hipStream_t stream) {
    const float* x = (const float*)d_in[0];
    float* out = (float*)d_out;
    k_stats<<<Z_DIM, 512, 0, stream>>>(x, out);
    k_h5<<<Z_DIM * 16, 256, 0, stream>>>(out, out);
}

// Round 6
// 308.619 us; speedup vs baseline: 1.6959x; 1.6959x over previous
//
#include <hip/hip_runtime.h>

// perm_inv_n: x[256,512,64] fp32 ->
//   per z (flat): cs[64] | gram[64x64] | ss[64] | cs^2[64] | (gram x cs)[64^3]
// FINAL (round-4 best, measurement reps removed). Two kernels:
//   k_stats: 1 block/z, 512 threads, 8x8-per-lane register tile; double-buffered
//     64-row chunks; in-LDS tree reduction. Measured S ~= 23 us (x8 rep = 184.1).
//   k_h5: 16 blocks/z, 256 threads; gram slab + cs staged in LDS; 64 KB
//     contiguous plain dwordx4 stores per block. Write-pinned (~18-43 us;
//     L2-absorbed with async drain).
// Session accounting (R4/R5 equation system, exact cross-check):
//   total 308.5 = F(~242-267 harness: 173 us poison fill @6.3TB/s + tiny
//   reset dispatches) + S(23) + H(18-43). Structure-invariant across 4
//   distinct implementations (308.5-314.2) -> harness-dominated floor.
#define Z_DIM 256
#define A_DIM 512
#define B_DIM 64
#define PER_Z 266432
#define GRAM_OFF 64
#define H3_OFF 4160
#define H4_OFF 4224
#define H5_OFF 4288

typedef float f4v __attribute__((ext_vector_type(4)));

__device__ __forceinline__ void wave_store_tile(float* area, const float acc[8][8],
                                                int R, int C) {
#pragma unroll
    for (int i = 0; i < 8; i++) {
        *(float4*)&area[(R + i) * B_DIM + C] =
            make_float4(acc[i][0], acc[i][1], acc[i][2], acc[i][3]);
        *(float4*)&area[(R + i) * B_DIM + C + 4] =
            make_float4(acc[i][4], acc[i][5], acc[i][6], acc[i][7]);
    }
}

__device__ __forceinline__ void wave_add_tile(const float* area, float acc[8][8],
                                              int R, int C) {
#pragma unroll
    for (int i = 0; i < 8; i++) {
        float4 p0 = *(const float4*)&area[(R + i) * B_DIM + C];
        float4 p1 = *(const float4*)&area[(R + i) * B_DIM + C + 4];
        acc[i][0] += p0.x; acc[i][1] += p0.y; acc[i][2] += p0.z; acc[i][3] += p0.w;
        acc[i][4] += p1.x; acc[i][5] += p1.y; acc[i][6] += p1.z; acc[i][7] += p1.w;
    }
}

__global__ __launch_bounds__(512) void k_stats(const float* __restrict__ x,
                                               float* __restrict__ out) {
    __shared__ float sx[2][B_DIM * B_DIM];  // 32 KB: dbuf staging, then 2 reduce areas
    __shared__ float csred[8][B_DIM];       // 2 KB cs partials

    const int z = blockIdx.x;
    const int t = threadIdx.x;
    const int w = t >> 6;       // wave 0..7
    const int l = t & 63;
    const int R = (l >> 3) * 8; // gram row-tile base
    const int C = (l & 7) * 8;  // gram col-tile base

    const float* xz = x + (size_t)z * (A_DIM * B_DIM);
    float* oz = out + (size_t)z * PER_Z;

    float acc[8][8];
#pragma unroll
    for (int i = 0; i < 8; i++)
#pragma unroll
        for (int j = 0; j < 8; j++) acc[i][j] = 0.f;
    float csa[8];
#pragma unroll
    for (int j = 0; j < 8; j++) csa[j] = 0.f;

    // prologue: stage chunk 0 (64 rows = 16 KB = 1024 float4, 2 per thread)
    {
        const float4* src = (const float4*)xz;
        float4 r0 = src[t], r1 = src[t + 512];
        ((float4*)sx[0])[t] = r0;
        ((float4*)sx[0])[t + 512] = r1;
    }
    __syncthreads();

    for (int c = 0; c < 8; ++c) {
        const float* buf = sx[c & 1];
        float4 n0, n1;
        if (c < 7) {  // issue next chunk's loads BEFORE compute (latency hides)
            const float4* src = (const float4*)(xz + (size_t)(c + 1) * 64 * B_DIM);
            n0 = src[t];
            n1 = src[t + 512];
        }
        // wave w computes rows [w*8, w*8+8) of this chunk against full 64x64 tile
        const float* rbase = buf + (w * 8) * B_DIM;
#pragma unroll
        for (int k = 0; k < 8; ++k) {
            const float* row = rbase + k * B_DIM;
            float4 b0 = *(const float4*)(row + R);
            float4 b1 = *(const float4*)(row + R + 4);
            float4 c0 = *(const float4*)(row + C);
            float4 c1 = *(const float4*)(row + C + 4);
            float xb[8] = {b0.x, b0.y, b0.z, b0.w, b1.x, b1.y, b1.z, b1.w};
            float xc[8] = {c0.x, c0.y, c0.z, c0.w, c1.x, c1.y, c1.z, c1.w};
#pragma unroll
            for (int i = 0; i < 8; i++)
#pragma unroll
                for (int j = 0; j < 8; j++)
                    acc[i][j] = fmaf(xb[i], xc[j], acc[i][j]);
            if (l < 8) {  // lanes 0-7 (R==0): cs partial for cols l*8..l*8+7
#pragma unroll
                for (int j = 0; j < 8; j++) csa[j] += xc[j];
            }
        }
        if (c < 7) {  // write next chunk into the other buffer (no read conflict)
            float* nb = sx[(c + 1) & 1];
            ((float4*)nb)[t] = n0;
            ((float4*)nb)[t + 512] = n1;
        }
        __syncthreads();
    }

    // cs partials -> LDS (read by wave 0 at the end, after several barriers)
    if (l < 8) {
#pragma unroll
        for (int j = 0; j < 8; j++) csred[w][l * 8 + j] = csa[j];
    }

    // tree-reduce 8 wave partials using sx[0]/sx[1] as two 16 KB areas
    float* area0 = sx[0];
    float* area1 = sx[1];
    if (w == 4) wave_store_tile(area0, acc, R, C);
    if (w == 5) wave_store_tile(area1, acc, R, C);
    __syncthreads();
    if (w == 0) wave_add_tile(area0, acc, R, C);
    if (w == 1) wave_add_tile(area1, acc, R, C);
    __syncthreads();
    if (w == 6) wave_store_tile(area0, acc, R, C);
    if (w == 7) wave_store_tile(area1, acc, R, C);
    __syncthreads();
    if (w == 2) wave_add_tile(area0, acc, R, C);
    if (w == 3) wave_add_tile(area1, acc, R, C);
    __syncthreads();
    if (w == 2) wave_store_tile(area0, acc, R, C);
    if (w == 3) wave_store_tile(area1, acc, R, C);
    __syncthreads();
    if (w == 0) wave_add_tile(area0, acc, R, C);
    if (w == 1) wave_add_tile(area1, acc, R, C);
    __syncthreads();
    if (w == 1) wave_store_tile(area0, acc, R, C);
    __syncthreads();

    if (w == 0) {
        wave_add_tile(area0, acc, R, C);  // final gram tile in wave 0's registers
        // h2: gram
#pragma unroll
        for (int i = 0; i < 8; i++) {
            *(float4*)&oz[GRAM_OFF + (size_t)(R + i) * B_DIM + C] =
                make_float4(acc[i][0], acc[i][1], acc[i][2], acc[i][3]);
            *(float4*)&oz[GRAM_OFF + (size_t)(R + i) * B_DIM + C + 4] =
                make_float4(acc[i][4], acc[i][5], acc[i][6], acc[i][7]);
        }
        // h3: diagonal (lanes whose tile straddles the diagonal: R==C)
        if ((l >> 3) == (l & 7)) {
#pragma unroll
            for (int i = 0; i < 8; i++) oz[H3_OFF + R + i] = acc[i][i];
        }
        // h1/h4: cs = sum of the 8 per-wave partials
        float cs = 0.f;
#pragma unroll
        for (int ww = 0; ww < 8; ww++) cs += csred[ww][l];
        oz[l] = cs;
        oz[H4_OFF + l] = cs * cs;
    }
}

// h5[b][c][d] = gram[b*64+c] * cs[d].  grid = 256 z * 16 slabs, 256 threads.
// Slab s covers bc in [s*256, s*256+256): 64 KB contiguous stores per block.
__global__ __launch_bounds__(256) void k_h5(const float* __restrict__ outc,
                                            float* __restrict__ out) {
    __shared__ __align__(16) float sgr[256];
    __shared__ __align__(16) float scs[B_DIM];

    const int z = blockIdx.x >> 4;
    const int s = blockIdx.x & 15;
    const int t = threadIdx.x;

    const float* oz = outc + (size_t)z * PER_Z;
    sgr[t] = oz[GRAM_OFF + s * 256 + t];   // one coalesced 1 KB load
    if (t < B_DIM) scs[t] = oz[t];
    __syncthreads();

    const int dg = t & 15;   // d-group: d = dg*4 .. dg*4+3
    const int bq = t >> 4;   // 0..15
    const f4v c4 = *(const f4v*)&scs[dg * 4];

    f4v* o5 = (f4v*)(out + (size_t)z * PER_Z + H5_OFF);
    const size_t base = (size_t)s * 4096 + bq * 16 + dg;
#pragma unroll
    for (int i = 0; i < 16; i++) {
        const float g = sgr[bq + i * 16];   // LDS broadcast, ~free
        f4v v = {g * c4.x, g * c4.y, g * c4.z, g * c4.w};
        o5[base + (size_t)i * 256] = v;     // per wave: 1 KB contiguous segment
    }
}

extern "C" void kernel_launch(void* const* d_in, const int* in_sizes, int n_in,
                              void* d_out, int out_size, void* d_ws, size_t ws_size,
                              hipStream_t stream) {
    const float* x = (const float*)d_in[0];
    float* out = (float*)d_out;
    k_stats<<<Z_DIM, 512, 0, stream>>>(x, out);
    k_h5<<<Z_DIM * 16, 256, 0, stream>>>(out, out);
}